// Round 4
// baseline (694.162 us; speedup 1.0000x reference)
//
#include <hip/hip_runtime.h>
#include <stdint.h>

#define N 8192
#define G 7
#define T 512
#define NW 8          // waves per block
typedef unsigned long long u64;
typedef uint32_t u32;

// Map float bits -> uint32 such that ascending uint order == DESCENDING float
// order, XLA total-order semantics. Stable LSD radix handles index tie-break.
__device__ __forceinline__ u32 enc_desc(float x) {
    u32 u = __float_as_uint(x);
    return (u & 0x80000000u) ? u : (~u & 0x7FFFFFFFu);
}
__device__ __forceinline__ float dec_desc(u32 k) {
    u32 u = (k & 0x80000000u) ? k : (~k & 0x7FFFFFFFu);
    return __uint_as_float(u);
}

// One radix pass on bits [SHIFT, SHIFT+8) of enc. Stable. LAST skips reload.
// enc/idx: 16 owned elements, element id e = (w<<10)|(j<<6)|lane.
template<int SHIFT, bool LAST>
__device__ __forceinline__ void radix_pass(
    u32* __restrict__ enc, u32* __restrict__ idx,
    u64* __restrict__ data, u32* __restrict__ wcnt, u32* __restrict__ dsum,
    int t, int w, int lane)
{
    const int wbase = w << 8;
    u32 rd[16];  // (digit << 16) | rank_within_wave

    // ---- phase A: stable in-wave rank + per-wave histogram ----
#pragma unroll
    for (int j = 0; j < 16; ++j) {
        u32 d = (enc[j] >> SHIFT) & 255u;           // v_bfe_u32 (const shift)
        u64 m = ~0ull;                              // same-digit lane mask
#pragma unroll
        for (int b = 0; b < 8; ++b) {
            bool pb = (d >> b) & 1u;
            u64 bb = __ballot(pb);
            m &= pb ? bb : ~bb;
        }
        u32 r = __builtin_amdgcn_mbcnt_hi((u32)(m >> 32),
                __builtin_amdgcn_mbcnt_lo((u32)m, 0u));  // popc(m & below)
        u32 base = wcnt[wbase + d];                 // broadcast within group
        rd[j] = (d << 16) | (base + r);
        if (r == 0)                                 // group leader bumps counter
            wcnt[wbase + d] = base + (u32)__popcll(m);
    }
    __syncthreads();

    // ---- scan: wave 0 only; lane owns digits 4*lane .. 4*lane+3 ----
    if (w == 0) {
        u32 run[4], s = 0;
#pragma unroll
        for (int q = 0; q < 4; ++q) {
            int d = 4 * lane + q;
            u32 acc = 0;
#pragma unroll
            for (int ww = 0; ww < NW; ++ww) {       // exclusive over waves
                u32 c = wcnt[(ww << 8) + d];
                wcnt[(ww << 8) + d] = acc;
                acc += c;
            }
            run[q] = acc;
            s += acc;
        }
        u32 v = s;                                  // inclusive shuffle scan
#pragma unroll
        for (int off = 1; off < 64; off <<= 1) {
            u32 u = __shfl_up(v, off, 64);
            if (lane >= off) v += u;
        }
        u32 a = v - s;                              // exclusive base for digit 4*lane
#pragma unroll
        for (int q = 0; q < 4; ++q) { dsum[4 * lane + q] = a; a += run[q]; }
    }
    __syncthreads();

    // ---- fold global digit base into per-wave bases ----
#pragma unroll
    for (int i = 0; i < 4; ++i) {
        int id = t + T * i;
        wcnt[id] += dsum[id & 255];
    }
    __syncthreads();

    // ---- scatter ----
#pragma unroll
    for (int j = 0; j < 16; ++j) {
        u32 pos = (rd[j] & 0xFFFFu) + wcnt[wbase + (rd[j] >> 16)];
        data[pos] = ((u64)enc[j] << 32) | idx[j];
    }
    __syncthreads();

    // ---- reload + zero counters for next pass ----
    if (!LAST) {
#pragma unroll
        for (int j = 0; j < 16; ++j) {
            u64 k = data[(w << 10) | (j << 6) | lane];
            enc[j] = (u32)(k >> 32);
            idx[j] = (u32)k;
        }
#pragma unroll
        for (int i = 0; i < 4; ++i) wcnt[t + T * i] = 0;
        __syncthreads();
    }
}

__global__ __launch_bounds__(T) void portfolio_radix_kernel(
    const float* __restrict__ x,
    float* __restrict__ bc,        // [B, N] float32
    float* __restrict__ idx_out)   // [B, N] indices as float32
{
    __shared__ u64 data[N];          // 64 KiB
    __shared__ u32 wcnt[NW * 256];   // 8 KiB
    __shared__ u32 dsum[256];        // 1 KiB

    const int t    = threadIdx.x;
    const int w    = t >> 6;
    const int lane = t & 63;
    const int row  = blockIdx.x;
    const float* xr = x + (size_t)row * N;

    // zero counters for pass 0
#pragma unroll
    for (int i = 0; i < 4; ++i) wcnt[t + T * i] = 0;

    // load + encode; ownership e = (w<<10)|(j<<6)|lane (coalesced 256B / slot)
    u32 enc[16], idx[16];
#pragma unroll
    for (int j = 0; j < 16; ++j) {
        int e = (w << 10) | (j << 6) | lane;
        enc[j] = enc_desc(xr[e]);
        idx[j] = (u32)e;
    }
    __syncthreads();

    radix_pass< 0, false>(enc, idx, data, wcnt, dsum, t, w, lane);
    radix_pass< 8, false>(enc, idx, data, wcnt, dsum, t, w, lane);
    radix_pass<16, false>(enc, idx, data, wcnt, dsum, t, w, lane);
    radix_pass<24, true >(enc, idx, data, wcnt, dsum, t, w, lane);

    // ---- outputs: data[] ascending in enc == descending in x ----
    float* bcr = bc + (size_t)row * N;
    float* ixr = idx_out + (size_t)row * N;
#pragma unroll
    for (int j = 0; j < 16; ++j) {
        int e = (w << 10) | (j << 6) | lane;     // coalesced per-slot stores
        u64 kk = data[e];
        ixr[e] = (float)(u32)(kk & 0xFFFFFFFFu);
        bcr[e] = 0.0f;
    }
    // winner: threads 0..6 (own positions 0..6) redundantly compute softmax(top-7)
    if (t < G) {
        float s[G], ex[G], sum = 0.f;
#pragma unroll
        for (int g = 0; g < G; ++g) s[g] = dec_desc((u32)(data[g] >> 32));
        float m0 = s[0];                          // max (descending values)
#pragma unroll
        for (int g = 0; g < G; ++g) { ex[g] = expf(s[g] - m0); sum += ex[g]; }
        bcr[t] = ex[t] / sum;
    }
    // loser: threads 505..511 (own positions N-7..N-1); -softmax(1-s) == -softmax(-s)
    if (t >= T - G) {
        float s[G], ex[G], sum = 0.f;
#pragma unroll
        for (int g = 0; g < G; ++g) s[g] = dec_desc((u32)(data[N - G + g] >> 32));
        float m0 = -s[G - 1];                     // max of -s (s descending)
#pragma unroll
        for (int g = 0; g < G; ++g) { ex[g] = expf(-s[g] - m0); sum += ex[g]; }
        bcr[(N - T) + t] = -ex[t - (T - G)] / sum;
    }
}

extern "C" void kernel_launch(void* const* d_in, const int* in_sizes, int n_in,
                              void* d_out, int out_size, void* d_ws, size_t ws_size,
                              hipStream_t stream) {
    const float* x = (const float*)d_in[0];
    float* out = (float*)d_out;
    const int B = in_sizes[0] / N;               // 4096
    float* bc  = out;                             // output 0: [B, N]
    float* idx = out + (size_t)B * N;             // output 1: [B, N] (as float32)
    portfolio_radix_kernel<<<B, T, 0, stream>>>(x, bc, idx);
}